// Round 2
// baseline (195.629 us; speedup 1.0000x reference)
//
#include <hip/hip_runtime.h>

// Round 7: K=4 batches per lane to break the LDS-BW wall.
// Rounds 5/6 both sat at ~125 us because weight ds_read_b128 traffic
// (4 KB/wave/site x 16 waves/CU = 64 KB/site/CU) saturates LDS read BW
// (~100 B/cy/CU); broadcast across identical batch-groups is still charged
// per lane. Now each lane carries v for 4 batches (strided bl = w*32+k*8+g),
// so the 4 weight reads/site are reused 4x: LDS reads/site/CU drop to
// ~20 KB and the kernel becomes VALU-issue-bound (~102 instr/site/wave).
// Geometry: 256 blocks x 256 thr; waves 0-1 = left chain, 2-3 = right chain,
// 64 batches per block, 1 block/CU, 1 wave/SIMD (all SIMDs covered).
// Staging is T14 async-split: global->reg issue right after the barrier,
// compute hides the latency, sched_barrier(0) + LDS writes at iteration end.

#define NSITES 784
#define DIM    8
#define ODIM   10
#define LABEL  392
#define WST    160   // words per staged site: 8 columns * 20-word stride
#define CST    20    // column stride (e*20 tiles all 32 banks)
#define XST    20    // xb row stride: 16 sites + 4 pad

// DPP ctrl encodings
#define QP_X1 0xB1   // quad_perm [1,0,3,2] : lane ^ 1
#define QP_X2 0x4E   // quad_perm [2,3,0,1] : lane ^ 2
#define QP_X3 0x1B   // quad_perm [3,2,1,0] : lane ^ 3
#define RHM   0x141  // row_half_mirror     : lane ^ 7 within each 8-lane group

template <int CTRL>
__device__ __forceinline__ float dppf(float v) {
    const int vi = __float_as_int(v);
    return __int_as_float(__builtin_amdgcn_update_dpp(vi, vi, CTRL, 0xF, 0xF, false));
}

struct W4 { float4 w00, w01, w10, w11; };

// One MPS site for one batch: weights shared across the lane's 4 batches.
__device__ __forceinline__ float site_step(float v, float p, const W4& w) {
    const float t1 = dppf<QP_X1>(v);   // v[e^1]
    const float t2 = dppf<QP_X2>(v);   // v[e^2]
    const float t3 = dppf<QP_X3>(v);   // v[e^3]
    const float t7 = dppf<RHM>(v);     // v[e^7]
    const float t6 = dppf<QP_X1>(t7);  // v[e^6]
    const float t5 = dppf<QP_X2>(t7);  // v[e^5]
    const float t4 = dppf<QP_X3>(t7);  // v[e^4]
    float a0 = v * w.w00.x;
    float a1 = v * w.w10.x;
    a0 = fmaf(t1, w.w00.y, a0);  a1 = fmaf(t1, w.w10.y, a1);
    a0 = fmaf(t2, w.w00.z, a0);  a1 = fmaf(t2, w.w10.z, a1);
    a0 = fmaf(t3, w.w00.w, a0);  a1 = fmaf(t3, w.w10.w, a1);
    a0 = fmaf(t4, w.w01.x, a0);  a1 = fmaf(t4, w.w11.x, a1);
    a0 = fmaf(t5, w.w01.y, a0);  a1 = fmaf(t5, w.w11.y, a1);
    a0 = fmaf(t6, w.w01.z, a0);  a1 = fmaf(t6, w.w11.z, a1);
    a0 = fmaf(t7, w.w01.w, a0);  a1 = fmaf(t7, w.w11.w, a1);
    return fmaf(p, a1 - a0, a0);     // (1-p)*a0 + p*a1
}

__global__ __launch_bounds__(256, 1) void mps_fused(
    const float* __restrict__ x,      // [B, N]
    const float* __restrict__ w0,     // [2, D]
    const float* __restrict__ Wl,     // [391, d, f, e]
    const float* __restrict__ wlab,   // [D, 2, D, O] = 1280 floats
    const float* __restrict__ Wr,     // [390, d, f, e]
    const float* __restrict__ wlast,  // [D, 2]
    float* __restrict__ out)          // [B, O]
{
    __shared__ float wb[2][2][16 * WST];  // [side][buf] 41.0 KB
    __shared__ float xb[2][2][64 * XST];  // [side][buf] 20.5 KB
    __shared__ float wl[1280];            // 5.1 KB
    __shared__ float vout[2][512];        // 4.0 KB

    const int tid  = threadIdx.x;
    const int side = tid >> 7;            // waves 0-1: left, waves 2-3: right
    const int stid = tid & 127;
    const int w    = stid >> 6;           // wave within side
    const int lane = stid & 63;
    const int g    = lane >> 3;           // batch group 0..7
    const int e    = lane & 7;            // owned bond index
    const int b0   = blockIdx.x * 64;
    // lane's 4 block-local batches: bl_k = w*32 + k*8 + g  (g-stride keeps
    // the per-k x float4 reads bank-conflict-free: g*20 words tiles banks)

    for (int k = tid; k < 320; k += 256)
        *(float4*)&wl[k * 4] = *(const float4*)&wlab[k * 4];

    // ------- staging registers (T14: load early, write late) -------
    float4 wr[4];
    float  xr[8];

    auto stage_load = [&](int c, int nt) {
        if (side == 0) {
            #pragma unroll
            for (int r = 0; r < 4; ++r) {
                const int cid = stid + 128 * r;       // 0..511
                const int s   = cid >> 5;
                const int u   = cid & 31;
                if (s < nt)
                    wr[r] = *(const float4*)(Wl + (size_t)(c * 16 + s) * 128
                                             + (u >> 2) * 16 + ((u >> 1) & 1) * 8 + (u & 1) * 4);
            }
            #pragma unroll
            for (int r = 0; r < 8; ++r) {
                const int cid = stid + 128 * r;       // 0..1023
                const int bl  = cid >> 4;
                const int sx  = cid & 15;
                if (sx < nt)
                    xr[r] = x[(size_t)(b0 + bl) * NSITES + 1 + c * 16 + sx];
            }
        } else {
            #pragma unroll
            for (int r = 0; r < 4; ++r) {
                const int cid = stid + 128 * r;
                const int s   = cid >> 5;
                const int u   = cid & 31;
                if (s < nt)
                    wr[r] = *(const float4*)(Wr + (size_t)(389 - c * 16 - s) * 128 + u * 4);
            }
            #pragma unroll
            for (int r = 0; r < 8; ++r) {
                const int cid = stid + 128 * r;
                const int bl  = cid >> 4;
                const int sx  = cid & 15;
                if (sx < nt)
                    xr[r] = x[(size_t)(b0 + bl) * NSITES + 782 - c * 16 - sx];
            }
        }
    };

    auto stage_write = [&](int bufi, int nt) {
        float* wdst = wb[side][bufi];
        float* xdst = xb[side][bufi];
        if (side == 0) {
            // W[d][f][e] -> wb[s][e*20 + f*8 + (e^d)]   (contract over d)
            #pragma unroll
            for (int r = 0; r < 4; ++r) {
                const int cid = stid + 128 * r;
                const int s   = cid >> 5;
                const int u   = cid & 31;
                const int d   = u >> 2;
                const int f   = (u >> 1) & 1;
                const int e0  = (u & 1) * 4;
                if (s < nt) {
                    float* dst = wdst + s * WST + f * 8;
                    dst[(e0 + 0) * CST + ((e0 + 0) ^ d)] = wr[r].x;
                    dst[(e0 + 1) * CST + ((e0 + 1) ^ d)] = wr[r].y;
                    dst[(e0 + 2) * CST + ((e0 + 2) ^ d)] = wr[r].z;
                    dst[(e0 + 3) * CST + ((e0 + 3) ^ d)] = wr[r].w;
                }
            }
        } else {
            // W[d][f][e] -> wb[s][d*20 + f*8 + (e^d)]   (contract over e)
            #pragma unroll
            for (int r = 0; r < 4; ++r) {
                const int cid = stid + 128 * r;
                const int s   = cid >> 5;
                const int u   = cid & 31;
                const int d   = u >> 2;
                const int k2  = u & 3;
                const int f   = k2 >> 1;
                const int e0  = (k2 & 1) * 4;
                if (s < nt) {
                    float* dst = wdst + s * WST + d * CST + f * 8;
                    dst[(e0 + 0) ^ d] = wr[r].x;
                    dst[(e0 + 1) ^ d] = wr[r].y;
                    dst[(e0 + 2) ^ d] = wr[r].z;
                    dst[(e0 + 3) ^ d] = wr[r].w;
                }
            }
        }
        #pragma unroll
        for (int r = 0; r < 8; ++r) {
            const int cid = stid + 128 * r;
            const int bl  = cid >> 4;
            const int sx  = cid & 15;
            if (sx < nt)
                xdst[bl * XST + sx] = xr[r];
        }
    };

    // ------- boundary init (4 batches per lane) -------
    float vv[4];
    if (side == 0) {
        #pragma unroll
        for (int k = 0; k < 4; ++k) {
            const int bl  = w * 32 + k * 8 + g;
            const float p = x[(size_t)(b0 + bl) * NSITES];
            vv[k] = fmaf(1.0f - p, w0[e], p * w0[DIM + e]);
        }
    } else {
        #pragma unroll
        for (int k = 0; k < 4; ++k) {
            const int bl  = w * 32 + k * 8 + g;
            const float p = x[(size_t)(b0 + bl) * NSITES + (NSITES - 1)];
            vv[k] = fmaf(1.0f - p, wlast[e * 2], p * wlast[e * 2 + 1]);
        }
    }

    const int nt_tail = side ? 6 : 7;

    stage_load(0, 16);
    stage_write(0, 16);
    int buf = 0;

    auto compute16 = [&](int bufi) {
        const float* wp = &wb[side][bufi][e * CST];
        const float* xp = &xb[side][bufi][(w * 32 + g) * XST];
        #pragma unroll
        for (int jb = 0; jb < 4; ++jb) {
            float4 xq[4];
            #pragma unroll
            for (int k = 0; k < 4; ++k)
                xq[k] = *(const float4*)(xp + k * 8 * XST + jb * 4);
            #pragma unroll
            for (int jj = 0; jj < 4; ++jj) {
                const int j = jb * 4 + jj;
                W4 wv;
                wv.w00 = *(const float4*)(wp + j * WST + 0);
                wv.w01 = *(const float4*)(wp + j * WST + 4);
                wv.w10 = *(const float4*)(wp + j * WST + 8);
                wv.w11 = *(const float4*)(wp + j * WST + 12);
                #pragma unroll
                for (int k = 0; k < 4; ++k) {
                    const float p = (jj == 0) ? xq[k].x : (jj == 1) ? xq[k].y
                                  : (jj == 2) ? xq[k].z : xq[k].w;
                    vv[k] = site_step(vv[k], p, wv);
                }
            }
        }
    };

    #pragma unroll 1
    for (int c = 0; c < 23; ++c) {           // chunks 0..22 (full)
        __syncthreads();                     // chunk c staged; buf^1 free
        stage_load(c + 1, 16);
        compute16(buf);
        __builtin_amdgcn_sched_barrier(0);   // keep writes after compute
        stage_write(buf ^ 1, 16);
        buf ^= 1;
    }

    // chunk 23 (full) + prefetch tail chunk 24
    __syncthreads();
    stage_load(24, nt_tail);
    compute16(buf);
    __builtin_amdgcn_sched_barrier(0);
    stage_write(buf ^ 1, nt_tail);
    buf ^= 1;

    // tail chunk 24 (7 sites left / 6 sites right)
    __syncthreads();
    {
        const float* wp = &wb[side][buf][e * CST];
        const float* xp = &xb[side][buf][(w * 32 + g) * XST];
        for (int j = 0; j < nt_tail; ++j) {
            W4 wv;
            wv.w00 = *(const float4*)(wp + j * WST + 0);
            wv.w01 = *(const float4*)(wp + j * WST + 4);
            wv.w10 = *(const float4*)(wp + j * WST + 8);
            wv.w11 = *(const float4*)(wp + j * WST + 12);
            #pragma unroll
            for (int k = 0; k < 4; ++k)
                vv[k] = site_step(vv[k], xp[k * 8 * XST + j], wv);
        }
    }

    // ------- publish bond vectors and combine at the label site -------
    #pragma unroll
    for (int k = 0; k < 4; ++k)
        vout[side][(w * 32 + k * 8 + g) * 8 + e] = vv[k];
    __syncthreads();

    for (int idx = tid; idx < 640; idx += 256) {   // 64 batches x 10 outputs
        const int bl = idx / 10;
        const int o  = idx - bl * 10;
        const float p = x[(size_t)(b0 + bl) * NSITES + LABEL];
        const float q = 1.0f - p;
        const float* vl = &vout[0][bl * 8];
        const float* rv = &vout[1][bl * 8];
        float acc = 0.0f;
        #pragma unroll
        for (int d = 0; d < DIM; ++d) {
            const float vld = vl[d];
            #pragma unroll
            for (int ee = 0; ee < DIM; ++ee) {
                const float m = fmaf(q, wl[((d * 2 + 0) * DIM + ee) * ODIM + o],
                                     p * wl[((d * 2 + 1) * DIM + ee) * ODIM + o]);
                acc = fmaf(vld * rv[ee], m, acc);
            }
        }
        out[(size_t)(b0 + bl) * ODIM + o] = acc;
    }
}

extern "C" void kernel_launch(void* const* d_in, const int* in_sizes, int n_in,
                              void* d_out, int out_size, void* d_ws, size_t ws_size,
                              hipStream_t stream) {
    (void)in_sizes; (void)n_in; (void)d_ws; (void)ws_size; (void)out_size;
    const float* x     = (const float*)d_in[0];
    const float* w0    = (const float*)d_in[1];
    const float* Wl    = (const float*)d_in[2];
    const float* wlab  = (const float*)d_in[3];
    const float* Wr    = (const float*)d_in[4];
    const float* wlast = (const float*)d_in[5];

    mps_fused<<<256, 256, 0, stream>>>(x, w0, Wl, wlab, Wr, wlast, (float*)d_out);
}

// Round 3
// 163.594 us; speedup vs baseline: 1.1958x; 1.1958x over previous
//
#include <hip/hip_runtime.h>

// Round 8: instruction-count attack via packed FP32.
// Empirical model from rounds 6/7: VALU issue = ~4 cy/wave-instr; round 6 was
// issue-saturated (80% busy) at ~38 instr/site/wave for 8 batches. This round
// serves 16 batches/wave in ~36 instr/site using v_pk_fma_f32 (2 fp32 FMA per
// instr, CDNA packed math):
//   - 2 batches packed per lane (K=2), accumulators/t-values as 64-bit pairs
//   - raw v_mov_b32_dpp asm (no tied-old copy; 7 dpp per 32-bit half)
//   - weights staged DUPLICATED [w,w] in LDS so each ds_read_b128 gives two
//     even-aligned broadcast pairs (q.xy/q.zw) -> no op_sel tricks, no movs
// Geometry: block 512 (waves 0-3 left / 4-7 right, same 64 batches), grid 256
// = 1 block/CU, 2 waves/SIMD (fixes round 7's 1-wave latency exposure).
// LDS ~98 KB. T14 async staging kept (load early / write late).

#define NSITES 784
#define DIM    8
#define ODIM   10
#define LABEL  392
#define WST2   288   // words per staged site: 8 columns * 36-word stride (dup weights)
#define CST2   36    // column stride: 32 dup-floats + 4 pad (banks 4e..4e+3 tiling)
#define XQST   34    // xb pair-row stride: 16 sites * 2 + 2 pad

typedef float v2f __attribute__((ext_vector_type(2)));

__device__ __forceinline__ float dpp_x1(float s) {
    float d; asm("v_mov_b32_dpp %0, %1 quad_perm:[1,0,3,2] row_mask:0xf bank_mask:0xf"
                 : "=v"(d) : "v"(s)); return d;
}
__device__ __forceinline__ float dpp_x2(float s) {
    float d; asm("v_mov_b32_dpp %0, %1 quad_perm:[2,3,0,1] row_mask:0xf bank_mask:0xf"
                 : "=v"(d) : "v"(s)); return d;
}
__device__ __forceinline__ float dpp_x3(float s) {
    float d; asm("v_mov_b32_dpp %0, %1 quad_perm:[3,2,1,0] row_mask:0xf bank_mask:0xf"
                 : "=v"(d) : "v"(s)); return d;
}
__device__ __forceinline__ float dpp_x7(float s) {
    float d; asm("v_mov_b32_dpp %0, %1 row_half_mirror row_mask:0xf bank_mask:0xf"
                 : "=v"(d) : "v"(s)); return d;
}

__device__ __forceinline__ v2f pk_mul(v2f a, v2f b) {
    v2f d; asm("v_pk_mul_f32 %0, %1, %2" : "=v"(d) : "v"(a), "v"(b)); return d;
}
__device__ __forceinline__ v2f pk_fma(v2f a, v2f b, v2f c) {
    v2f d; asm("v_pk_fma_f32 %0, %1, %2, %3" : "=v"(d) : "v"(a), "v"(b), "v"(c)); return d;
}
__device__ __forceinline__ v2f pk_add(v2f a, v2f b) {
    v2f d; asm("v_pk_add_f32 %0, %1, %2" : "=v"(d) : "v"(a), "v"(b)); return d;
}

__device__ __forceinline__ v2f XY(const float4& q) { v2f r = {q.x, q.y}; return r; }
__device__ __forceinline__ v2f ZW(const float4& q) { v2f r = {q.z, q.w}; return r; }

// One MPS site for 2 packed batches. wc = lane's 32-float dup column.
__device__ __forceinline__ v2f site_step2(v2f v, v2f p, const float* wc) {
    const float4 q0 = *(const float4*)(wc + 0);    // f0: m0,m1 (dup pairs)
    const float4 q1 = *(const float4*)(wc + 4);    // f0: m2,m3
    const float4 q2 = *(const float4*)(wc + 8);    // f0: m4,m5
    const float4 q3 = *(const float4*)(wc + 12);   // f0: m6,m7
    const float4 q4 = *(const float4*)(wc + 16);   // f1: m0,m1
    const float4 q5 = *(const float4*)(wc + 20);   // f1: m2,m3
    const float4 q6 = *(const float4*)(wc + 24);   // f1: m4,m5
    const float4 q7 = *(const float4*)(wc + 28);   // f1: m6,m7
    v2f t1; t1.x = dpp_x1(v.x); t1.y = dpp_x1(v.y);   // v[e^1]
    v2f t2; t2.x = dpp_x2(v.x); t2.y = dpp_x2(v.y);   // v[e^2]
    v2f t3; t3.x = dpp_x3(v.x); t3.y = dpp_x3(v.y);   // v[e^3]
    v2f t7; t7.x = dpp_x7(v.x); t7.y = dpp_x7(v.y);   // v[e^7]
    v2f t6; t6.x = dpp_x1(t7.x); t6.y = dpp_x1(t7.y); // v[e^6]
    v2f t5; t5.x = dpp_x2(t7.x); t5.y = dpp_x2(t7.y); // v[e^5]
    v2f t4; t4.x = dpp_x3(t7.x); t4.y = dpp_x3(t7.y); // v[e^4]
    v2f a00 = pk_mul(v,  XY(q0)); a00 = pk_fma(t1, ZW(q0), a00);
    a00 = pk_fma(t2, XY(q1), a00); a00 = pk_fma(t3, ZW(q1), a00);
    v2f a01 = pk_mul(t4, XY(q2)); a01 = pk_fma(t5, ZW(q2), a01);
    a01 = pk_fma(t6, XY(q3), a01); a01 = pk_fma(t7, ZW(q3), a01);
    v2f a10 = pk_mul(v,  XY(q4)); a10 = pk_fma(t1, ZW(q4), a10);
    a10 = pk_fma(t2, XY(q5), a10); a10 = pk_fma(t3, ZW(q5), a10);
    v2f a11 = pk_mul(t4, XY(q6)); a11 = pk_fma(t5, ZW(q6), a11);
    a11 = pk_fma(t6, XY(q7), a11); a11 = pk_fma(t7, ZW(q7), a11);
    const v2f a0 = pk_add(a00, a01);
    const v2f a1 = pk_add(a10, a11);
    v2f r;
    r.x = fmaf(p.x, a1.x - a0.x, a0.x);
    r.y = fmaf(p.y, a1.y - a0.y, a0.y);
    return r;
}

__global__ __launch_bounds__(512, 2) void mps_fused(
    const float* __restrict__ x,      // [B, N]
    const float* __restrict__ w0,     // [2, D]
    const float* __restrict__ Wl,     // [391, d, f, e]
    const float* __restrict__ wlab,   // [D, 2, D, O] = 1280 floats
    const float* __restrict__ Wr,     // [390, d, f, e]
    const float* __restrict__ wlast,  // [D, 2]
    float* __restrict__ out)          // [B, O]
{
    __shared__ float wb[2][2][16 * WST2];   // [side][buf] 72.0 KB (dup weights)
    __shared__ float xb[2][2][32 * XQST];   // [side][buf] 17.0 KB (pair-interleaved)
    __shared__ float wl[1280];              // 5.1 KB
    __shared__ float vout[2][512];          // 4.0 KB

    const int tid   = threadIdx.x;
    const int side  = tid >> 8;             // waves 0-3: left, 4-7: right
    const int stid2 = tid & 255;
    const int w     = stid2 >> 6;           // wave within side 0..3
    const int lane  = stid2 & 63;
    const int g     = lane >> 3;            // batch-pair group 0..7
    const int e     = lane & 7;             // owned bond index
    const int pr    = w * 8 + g;            // pair index 0..31
    const int b0    = blockIdx.x * 64;      // 64 batches per block

    if (tid < 320)
        *(float4*)&wl[tid * 4] = *(const float4*)&wlab[tid * 4];

    // ------- staging registers (T14: load early, write late) -------
    float4 wr[2];
    float  xr[4];

    auto stage_load = [&](int c, int nt) {
        const float* W = side == 0 ? Wl : Wr;
        #pragma unroll
        for (int r = 0; r < 2; ++r) {
            const int cid = stid2 + 256 * r;        // 0..511 = 16 sites x 32
            const int s   = cid >> 5;
            const int u   = cid & 31;
            if (s < nt) {
                const int row = side == 0 ? (c * 16 + s) : (389 - c * 16 - s);
                wr[r] = *(const float4*)(W + (size_t)row * 128 + u * 4);
            }
        }
        #pragma unroll
        for (int r = 0; r < 4; ++r) {
            const int cid = stid2 + 256 * r;        // 0..1023 = 64 b x 16 s
            const int bl  = cid >> 4;
            const int sx  = cid & 15;
            if (sx < nt) {
                const int col = side == 0 ? (1 + c * 16 + sx) : (782 - c * 16 - sx);
                xr[r] = x[(size_t)(b0 + bl) * NSITES + col];
            }
        }
    };

    auto stage_write = [&](int bufi, int nt) {
        float* wdst = wb[side][bufi];
        float* xdst = xb[side][bufi];
        #pragma unroll
        for (int r = 0; r < 2; ++r) {
            const int cid = stid2 + 256 * r;
            const int s   = cid >> 5;
            const int u   = cid & 31;
            const int d   = u >> 2;
            const int f   = (u >> 1) & 1;
            const int e0  = (u & 1) * 4;
            if (s < nt) {
                if (side == 0) {
                    // left: column = output bond e, slot m = e^d (contract d)
                    float* dst = wdst + s * WST2 + f * 16;
                    v2f c0 = {wr[r].x, wr[r].x};
                    v2f c1 = {wr[r].y, wr[r].y};
                    v2f c2 = {wr[r].z, wr[r].z};
                    v2f c3 = {wr[r].w, wr[r].w};
                    *(v2f*)(dst + (e0 + 0) * CST2 + ((e0 + 0) ^ d) * 2) = c0;
                    *(v2f*)(dst + (e0 + 1) * CST2 + ((e0 + 1) ^ d) * 2) = c1;
                    *(v2f*)(dst + (e0 + 2) * CST2 + ((e0 + 2) ^ d) * 2) = c2;
                    *(v2f*)(dst + (e0 + 3) * CST2 + ((e0 + 3) ^ d) * 2) = c3;
                } else {
                    // right: column = output bond d, slot m = e^d (contract e)
                    float* dst = wdst + s * WST2 + d * CST2 + f * 16;
                    v2f c0 = {wr[r].x, wr[r].x};
                    v2f c1 = {wr[r].y, wr[r].y};
                    v2f c2 = {wr[r].z, wr[r].z};
                    v2f c3 = {wr[r].w, wr[r].w};
                    *(v2f*)(dst + ((e0 + 0) ^ d) * 2) = c0;
                    *(v2f*)(dst + ((e0 + 1) ^ d) * 2) = c1;
                    *(v2f*)(dst + ((e0 + 2) ^ d) * 2) = c2;
                    *(v2f*)(dst + ((e0 + 3) ^ d) * 2) = c3;
                }
            }
        }
        #pragma unroll
        for (int r = 0; r < 4; ++r) {
            const int cid  = stid2 + 256 * r;
            const int bl   = cid >> 4;
            const int sx   = cid & 15;
            const int prw  = bl >> 1;
            const int half = bl & 1;
            if (sx < nt)
                xdst[prw * XQST + sx * 2 + half] = xr[r];
        }
    };

    // ------- boundary init (2 packed batches per lane) -------
    v2f vv;
    if (side == 0) {
        const float p0 = x[(size_t)(b0 + 2 * pr + 0) * NSITES];
        const float p1 = x[(size_t)(b0 + 2 * pr + 1) * NSITES];
        vv.x = fmaf(1.0f - p0, w0[e], p0 * w0[DIM + e]);
        vv.y = fmaf(1.0f - p1, w0[e], p1 * w0[DIM + e]);
    } else {
        const float p0 = x[(size_t)(b0 + 2 * pr + 0) * NSITES + (NSITES - 1)];
        const float p1 = x[(size_t)(b0 + 2 * pr + 1) * NSITES + (NSITES - 1)];
        vv.x = fmaf(1.0f - p0, wlast[e * 2], p0 * wlast[e * 2 + 1]);
        vv.y = fmaf(1.0f - p1, wlast[e * 2], p1 * wlast[e * 2 + 1]);
    }

    const int nt_tail = side ? 6 : 7;

    stage_load(0, 16);
    stage_write(0, 16);
    int buf = 0;

    auto compute16 = [&](int bufi) {
        const float* wp = &wb[side][bufi][e * CST2];
        const float* xp = &xb[side][bufi][pr * XQST];
        #pragma unroll
        for (int jh = 0; jh < 8; ++jh) {
            const float4 xq = *(const float4*)(xp + jh * 4);   // p for 2 sites x pair
            v2f pa; pa.x = xq.x; pa.y = xq.y;
            v2f pb; pb.x = xq.z; pb.y = xq.w;
            vv = site_step2(vv, pa, wp + (2 * jh + 0) * WST2);
            vv = site_step2(vv, pb, wp + (2 * jh + 1) * WST2);
        }
    };

    #pragma unroll 1
    for (int c = 0; c < 23; ++c) {            // chunks 0..22 (full)
        __syncthreads();                      // chunk c staged; buf^1 free
        stage_load(c + 1, 16);
        compute16(buf);
        __builtin_amdgcn_sched_barrier(0);    // keep LDS writes after compute
        stage_write(buf ^ 1, 16);
        buf ^= 1;
    }

    // chunk 23 (full) + prefetch tail chunk 24
    __syncthreads();
    stage_load(24, nt_tail);
    compute16(buf);
    __builtin_amdgcn_sched_barrier(0);
    stage_write(buf ^ 1, nt_tail);
    buf ^= 1;

    // tail chunk 24 (7 sites left / 6 sites right)
    __syncthreads();
    {
        const float* wp = &wb[side][buf][e * CST2];
        const float* xp = &xb[side][buf][pr * XQST];
        for (int j = 0; j < nt_tail; ++j) {
            v2f p; p.x = xp[j * 2]; p.y = xp[j * 2 + 1];
            vv = site_step2(vv, p, wp + j * WST2);
        }
    }

    // ------- publish bond vectors and combine at the label site -------
    vout[side][(2 * pr + 0) * 8 + e] = vv.x;
    vout[side][(2 * pr + 1) * 8 + e] = vv.y;
    __syncthreads();

    for (int idx = tid; idx < 640; idx += 512) {   // 64 batches x 10 outputs
        const int bl = idx / 10;
        const int o  = idx - bl * 10;
        const float p = x[(size_t)(b0 + bl) * NSITES + LABEL];
        const float q = 1.0f - p;
        const float* vl = &vout[0][bl * 8];
        const float* rv = &vout[1][bl * 8];
        float acc = 0.0f;
        #pragma unroll
        for (int d = 0; d < DIM; ++d) {
            const float vld = vl[d];
            #pragma unroll
            for (int ee = 0; ee < DIM; ++ee) {
                const float m = fmaf(q, wl[((d * 2 + 0) * DIM + ee) * ODIM + o],
                                     p * wl[((d * 2 + 1) * DIM + ee) * ODIM + o]);
                acc = fmaf(vld * rv[ee], m, acc);
            }
        }
        out[(size_t)(b0 + bl) * ODIM + o] = acc;
    }
}

extern "C" void kernel_launch(void* const* d_in, const int* in_sizes, int n_in,
                              void* d_out, int out_size, void* d_ws, size_t ws_size,
                              hipStream_t stream) {
    (void)in_sizes; (void)n_in; (void)d_ws; (void)ws_size; (void)out_size;
    const float* x     = (const float*)d_in[0];
    const float* w0    = (const float*)d_in[1];
    const float* Wl    = (const float*)d_in[2];
    const float* wlab  = (const float*)d_in[3];
    const float* Wr    = (const float*)d_in[4];
    const float* wlast = (const float*)d_in[5];

    mps_fused<<<256, 512, 0, stream>>>(x, w0, Wl, wlab, Wr, wlast, (float*)d_out);
}

// Round 4
// 154.015 us; speedup vs baseline: 1.2702x; 1.0622x over previous
//
#include <hip/hip_runtime.h>

// Round 9: e-pair packing — pack the OUTPUT bond pair (2q,2q+1) per lane
// instead of 2 batches. XOR-term sources then pair up: term m needs
// (v[e0^m], v[e1^m]) = {own, quad_perm q^1, q^2, q^3}, each used twice —
// direct and half-swapped via VOP3P op_sel (free). DPP/site: 14 -> 6;
// blend p-broadcast also via op_sel. 24 VALU/site vs round 8's 34, same
// 8 ds_read_b128/site, weights un-dup'd (LDS halves -> 54 KB/block).
// Geometry: 512 blocks x 256 thr (2 waves left + 2 right, 32 batches),
// 2 blocks/CU x 4 waves = 2 waves/SIMD; two independent barrier groups
// per CU overlap each other's staging stalls. T14 async staging kept.

#define NSITES 784
#define DIM    8
#define ODIM   10
#define LABEL  392
#define WSITE  144   // floats per staged site: 4 q-columns * 36
#define QST    36    // column stride: 32 + 4 pad -> column q at banks 4q..4q+3
#define XST    20    // xb row stride: 16 sites + 4 pad

typedef float v2f __attribute__((ext_vector_type(2)));

// quad_perm rotations on q (each 4-lane quad = one batch group)
__device__ __forceinline__ float dpp_q1(float s){float d;asm("v_mov_b32_dpp %0, %1 quad_perm:[1,0,3,2] row_mask:0xf bank_mask:0xf":"=v"(d):"v"(s));return d;}
__device__ __forceinline__ float dpp_q2(float s){float d;asm("v_mov_b32_dpp %0, %1 quad_perm:[2,3,0,1] row_mask:0xf bank_mask:0xf":"=v"(d):"v"(s));return d;}
__device__ __forceinline__ float dpp_q3(float s){float d;asm("v_mov_b32_dpp %0, %1 quad_perm:[3,2,1,0] row_mask:0xf bank_mask:0xf":"=v"(d):"v"(s));return d;}

__device__ __forceinline__ v2f pk_mul(v2f a, v2f b){v2f d;asm("v_pk_mul_f32 %0,%1,%2":"=v"(d):"v"(a),"v"(b));return d;}
__device__ __forceinline__ v2f pk_fma(v2f a, v2f b, v2f c){v2f d;asm("v_pk_fma_f32 %0,%1,%2,%3":"=v"(d):"v"(a),"v"(b),"v"(c));return d;}
// src0 half-swapped: lo result uses src0.hi, hi result uses src0.lo
__device__ __forceinline__ v2f pk_fma_s(v2f a, v2f b, v2f c){v2f d;asm("v_pk_fma_f32 %0,%1,%2,%3 op_sel:[1,0,0] op_sel_hi:[0,1,1]":"=v"(d):"v"(a),"v"(b),"v"(c));return d;}
// src0 broadcast lo / broadcast hi (for the per-site p blend)
__device__ __forceinline__ v2f pk_fma_blo(v2f a, v2f b, v2f c){v2f d;asm("v_pk_fma_f32 %0,%1,%2,%3 op_sel:[0,0,0] op_sel_hi:[0,1,1]":"=v"(d):"v"(a),"v"(b),"v"(c));return d;}
__device__ __forceinline__ v2f pk_fma_bhi(v2f a, v2f b, v2f c){v2f d;asm("v_pk_fma_f32 %0,%1,%2,%3 op_sel:[1,0,0] op_sel_hi:[1,1,1]":"=v"(d):"v"(a),"v"(b),"v"(c));return d;}
// a - b
__device__ __forceinline__ v2f pk_sub(v2f a, v2f b){v2f d;asm("v_pk_add_f32 %0,%1,%2 neg_lo:[0,1] neg_hi:[0,1]":"=v"(d):"v"(a),"v"(b));return d;}

__device__ __forceinline__ v2f XY(const float4& q){ v2f r = {q.x, q.y}; return r; }
__device__ __forceinline__ v2f ZW(const float4& q){ v2f r = {q.z, q.w}; return r; }

// One MPS site for one batch, output pair (2q,2q+1) per lane.
// wc = lane's 32-float column: pair slot idx = f*8+m at floats idx*2..idx*2+1.
template <bool PHI>
__device__ __forceinline__ v2f site_step(v2f v, const float* wc, v2f pp) {
    const float4 r0 = *(const float4*)(wc + 0);    // f0 m0,m1
    const float4 r1 = *(const float4*)(wc + 4);    // f0 m2,m3
    const float4 r2 = *(const float4*)(wc + 8);    // f0 m4,m5
    const float4 r3 = *(const float4*)(wc + 12);   // f0 m6,m7
    const float4 r4 = *(const float4*)(wc + 16);   // f1 m0,m1
    const float4 r5 = *(const float4*)(wc + 20);   // f1 m2,m3
    const float4 r6 = *(const float4*)(wc + 24);   // f1 m4,m5
    const float4 r7 = *(const float4*)(wc + 28);   // f1 m6,m7
    v2f d1; d1.x = dpp_q1(v.x); d1.y = dpp_q1(v.y);   // v[·^2] pairs
    v2f d2; d2.x = dpp_q2(v.x); d2.y = dpp_q2(v.y);   // v[·^4] pairs
    v2f d3; d3.x = dpp_q3(v.x); d3.y = dpp_q3(v.y);   // v[·^6] pairs
    v2f a0 = pk_mul (v,  XY(r0));        // m0
    a0 = pk_fma_s(v,  ZW(r0), a0);       // m1 (swap)
    a0 = pk_fma  (d1, XY(r1), a0);       // m2
    a0 = pk_fma_s(d1, ZW(r1), a0);       // m3
    a0 = pk_fma  (d2, XY(r2), a0);       // m4
    a0 = pk_fma_s(d2, ZW(r2), a0);       // m5
    a0 = pk_fma  (d3, XY(r3), a0);       // m6
    a0 = pk_fma_s(d3, ZW(r3), a0);       // m7
    v2f a1 = pk_mul (v,  XY(r4));
    a1 = pk_fma_s(v,  ZW(r4), a1);
    a1 = pk_fma  (d1, XY(r5), a1);
    a1 = pk_fma_s(d1, ZW(r5), a1);
    a1 = pk_fma  (d2, XY(r6), a1);
    a1 = pk_fma_s(d2, ZW(r6), a1);
    a1 = pk_fma  (d3, XY(r7), a1);
    a1 = pk_fma_s(d3, ZW(r7), a1);
    const v2f df = pk_sub(a1, a0);
    return PHI ? pk_fma_bhi(pp, df, a0) : pk_fma_blo(pp, df, a0);
}

__global__ __launch_bounds__(256, 2) void mps_fused(
    const float* __restrict__ x,      // [B, N]
    const float* __restrict__ w0,     // [2, D]
    const float* __restrict__ Wl,     // [391, d, f, e]
    const float* __restrict__ wlab,   // [D, 2, D, O] = 1280 floats
    const float* __restrict__ Wr,     // [390, d, f, e]
    const float* __restrict__ wlast,  // [D, 2]
    float* __restrict__ out)          // [B, O]
{
    __shared__ float wb[2][2][16 * WSITE];  // [side][buf] 36.9 KB
    __shared__ float xb[2][2][32 * XST];    // [side][buf] 10.2 KB
    __shared__ float wl[1280];              // 5.1 KB
    __shared__ float vout[2][256];          // 2.0 KB          (~54 KB total)

    const int tid  = threadIdx.x;
    const int side = tid >> 7;              // waves 0-1: left, 2-3: right
    const int stid = tid & 127;
    const int w    = stid >> 6;             // wave within side 0..1
    const int lane = stid & 63;
    const int q    = lane & 3;              // output-pair index (e = 2q, 2q+1)
    const int grp  = lane >> 2;             // batch group 0..15
    const int bl   = w * 16 + grp;          // block-local batch 0..31
    const int b0   = blockIdx.x * 32;

    for (int k = tid; k < 320; k += 256)
        *(float4*)&wl[k * 4] = *(const float4*)&wlab[k * 4];

    // ------- staging registers (T14: load early, write late) -------
    float4 wr[4];
    float  xr[4];

    auto stage_load = [&](int c, int nt) {
        const float* W = side == 0 ? Wl : Wr;
        #pragma unroll
        for (int r = 0; r < 4; ++r) {
            const int cid = stid + 128 * r;        // 0..511 = 16 sites x 32
            const int s   = cid >> 5;
            const int u   = cid & 31;
            if (s < nt) {
                const int row = side == 0 ? (c * 16 + s) : (389 - c * 16 - s);
                wr[r] = *(const float4*)(W + (size_t)row * 128 + u * 4);
            }
        }
        #pragma unroll
        for (int r = 0; r < 4; ++r) {
            const int cid = stid + 128 * r;        // 0..511 = 32 b x 16 s
            const int b   = cid >> 4;
            const int sx  = cid & 15;
            if (sx < nt) {
                const int col = side == 0 ? (1 + c * 16 + sx) : (782 - c * 16 - sx);
                xr[r] = x[(size_t)(b0 + b) * NSITES + col];
            }
        }
    };

    // scatter: left  W[d][f][e] -> [e>>1]*36 + (f*8 + (e^d))*2 + (e&1)
    //          right W[d][f][e] -> [d>>1]*36 + (f*8 + (d^e))*2 + (d&1)
    auto stage_write = [&](int bufi, int nt) {
        float* wdst = wb[side][bufi];
        float* xdst = xb[side][bufi];
        #pragma unroll
        for (int r = 0; r < 4; ++r) {
            const int cid = stid + 128 * r;
            const int s   = cid >> 5;
            const int u   = cid & 31;
            const int d   = u >> 2;
            const int f   = (u >> 1) & 1;
            const int e4  = (u & 1) * 4;
            if (s < nt) {
                float* dst = wdst + s * WSITE;
                const float vals[4] = {wr[r].x, wr[r].y, wr[r].z, wr[r].w};
                #pragma unroll
                for (int k = 0; k < 4; ++k) {
                    const int e = e4 + k;
                    if (side == 0)
                        dst[(e >> 1) * QST + (f * 8 + (e ^ d)) * 2 + (e & 1)] = vals[k];
                    else
                        dst[(d >> 1) * QST + (f * 8 + (d ^ e)) * 2 + (d & 1)] = vals[k];
                }
            }
        }
        #pragma unroll
        for (int r = 0; r < 4; ++r) {
            const int cid = stid + 128 * r;
            const int b   = cid >> 4;
            const int sx  = cid & 15;
            if (sx < nt)
                xdst[b * XST + sx] = xr[r];
        }
    };

    // ------- boundary init: output pair (2q, 2q+1) for batch bl -------
    v2f vv;
    {
        const int e0 = 2 * q, e1 = 2 * q + 1;
        if (side == 0) {
            const float p = x[(size_t)(b0 + bl) * NSITES];
            vv.x = fmaf(1.0f - p, w0[e0], p * w0[DIM + e0]);
            vv.y = fmaf(1.0f - p, w0[e1], p * w0[DIM + e1]);
        } else {
            const float p = x[(size_t)(b0 + bl) * NSITES + (NSITES - 1)];
            vv.x = fmaf(1.0f - p, wlast[e0 * 2], p * wlast[e0 * 2 + 1]);
            vv.y = fmaf(1.0f - p, wlast[e1 * 2], p * wlast[e1 * 2 + 1]);
        }
    }

    const int nt_tail = side ? 6 : 7;

    stage_load(0, 16);
    stage_write(0, 16);
    int buf = 0;

    auto compute16 = [&](int bufi) {
        const float* wp = &wb[side][bufi][q * QST];
        const float* xp = &xb[side][bufi][bl * XST];
        #pragma unroll
        for (int jb = 0; jb < 4; ++jb) {
            const float4 xq = *(const float4*)(xp + jb * 4);  // p for 4 sites
            const v2f p01 = XY(xq);
            const v2f p23 = ZW(xq);
            vv = site_step<false>(vv, wp + (jb * 4 + 0) * WSITE, p01);
            vv = site_step<true >(vv, wp + (jb * 4 + 1) * WSITE, p01);
            vv = site_step<false>(vv, wp + (jb * 4 + 2) * WSITE, p23);
            vv = site_step<true >(vv, wp + (jb * 4 + 3) * WSITE, p23);
        }
    };

    #pragma unroll 1
    for (int c = 0; c < 23; ++c) {            // chunks 0..22 (full)
        __syncthreads();                      // chunk c staged; buf^1 free
        stage_load(c + 1, 16);
        compute16(buf);
        __builtin_amdgcn_sched_barrier(0);    // keep LDS writes after compute
        stage_write(buf ^ 1, 16);
        buf ^= 1;
    }

    // chunk 23 (full) + prefetch tail chunk 24
    __syncthreads();
    stage_load(24, nt_tail);
    compute16(buf);
    __builtin_amdgcn_sched_barrier(0);
    stage_write(buf ^ 1, nt_tail);
    buf ^= 1;

    // tail chunk 24 (7 sites left / 6 sites right)
    __syncthreads();
    {
        const float* wp = &wb[side][buf][q * QST];
        const float* xp = &xb[side][buf][bl * XST];
        for (int j = 0; j < nt_tail; ++j) {
            v2f pp; pp.x = xp[j]; pp.y = pp.x;
            vv = site_step<false>(vv, wp + j * WSITE, pp);
        }
    }

    // ------- publish bond vectors and combine at the label site -------
    *(v2f*)&vout[side][bl * 8 + 2 * q] = vv;
    __syncthreads();

    for (int idx = tid; idx < 320; idx += 256) {   // 32 batches x 10 outputs
        const int b = idx / 10;
        const int o = idx - b * 10;
        const float p = x[(size_t)(b0 + b) * NSITES + LABEL];
        const float qq = 1.0f - p;
        const float* vl = &vout[0][b * 8];
        const float* rv = &vout[1][b * 8];
        float acc = 0.0f;
        #pragma unroll
        for (int d = 0; d < DIM; ++d) {
            const float vld = vl[d];
            #pragma unroll
            for (int ee = 0; ee < DIM; ++ee) {
                const float m = fmaf(qq, wl[((d * 2 + 0) * DIM + ee) * ODIM + o],
                                     p * wl[((d * 2 + 1) * DIM + ee) * ODIM + o]);
                acc = fmaf(vld * rv[ee], m, acc);
            }
        }
        out[(size_t)(b0 + b) * ODIM + o] = acc;
    }
}

extern "C" void kernel_launch(void* const* d_in, const int* in_sizes, int n_in,
                              void* d_out, int out_size, void* d_ws, size_t ws_size,
                              hipStream_t stream) {
    (void)in_sizes; (void)n_in; (void)d_ws; (void)ws_size; (void)out_size;
    const float* x     = (const float*)d_in[0];
    const float* w0    = (const float*)d_in[1];
    const float* Wl    = (const float*)d_in[2];
    const float* wlab  = (const float*)d_in[3];
    const float* Wr    = (const float*)d_in[4];
    const float* wlast = (const float*)d_in[5];

    mps_fused<<<512, 256, 0, stream>>>(x, w0, Wl, wlab, Wr, wlast, (float*)d_out);
}